// Round 14
// baseline (371.399 us; speedup 1.0000x reference)
//
#include <hip/hip_runtime.h>

#define BATCH 16384
#define NUM   512
#define CONS  512
#define ROWS  8                     // rows per wave/block
#define ZOFF  (NUM*16)              // 8192: 8 zero dummy atoms x 16B
#define OOFF  (NUM*16 + 128)        // 8320: 8 one dummy atoms x 16B
#define LDSB  (NUM*16 + 256)        // 8448 B
#define NPAD  520                   // 512 real + 8 pad records (pipeline depth)
#define RSTR  84                    // record words per constraint

typedef _Float16 h2 __attribute__((ext_vector_type(2)));
static __device__ __forceinline__ h2 u2h(unsigned u){ return __builtin_bit_cast(h2,u); }
static __device__ __forceinline__ unsigned h2u(h2 h){ return __builtin_bit_cast(unsigned,h); }
static __device__ __forceinline__ h2 hmax2(h2 a,h2 b){ return __builtin_elementwise_max(a,b); }
static __device__ __forceinline__ h2 hmin2(h2 a,h2 b){ return __builtin_elementwise_min(a,b); }
static __device__ __forceinline__ h2 ldsv(const char* Pb, unsigned off) {
  return *(volatile const h2*)(Pb + off);     // volatile: not sinkable by compiler
}
template<int C>
static __device__ __forceinline__ h2 dppmax(h2 x) {
  unsigned v = (unsigned)__builtin_amdgcn_mov_dpp((int)h2u(x), C, 0xF, 0xF, true);
  return hmax2(x, u2h(v));
}

// record (RSTR words per c):
// [0..15]=N steps(0,1) packed u16 pairs by g; [16..31]=N steps(2,3);
// [32..47]=P steps(0,1); [48..63]=P steps(2,3); [64]= ho | fl<<16;
// [65..72]=N extras; [73..80]=P extras; [81..83]=pad.
// fl: 0 sign |1 N1 |2 P1 |3 N2 |4 P2 |5 PR1 |6 PR2 |7-10 exN |11-14 exP |15 SKIP
__global__ __launch_bounds__(64) void prep_kernel(
    const float* __restrict__ pos, const float* __restrict__ neg,
    const int* __restrict__ head_atom, const int* __restrict__ head_sign,
    unsigned* __restrict__ ents) {
  int c = blockIdx.x, lane = threadIdx.x;
  unsigned* rec = ents + (size_t)c * RSTR;
  __shared__ unsigned short slotN[64], slotP[64];
  __shared__ unsigned char  usedN[64], usedP[64];
  __shared__ unsigned short spillN[8][12], spillP[8][12];
  __shared__ unsigned char  spnN[8], spnP[8];
  __shared__ unsigned short exN[8], exP[8];
  __shared__ int exn, exp_;
  slotN[lane] = (unsigned short)(ZOFF + (lane & 7) * 16);   // residue-matched dummies
  slotP[lane] = (unsigned short)(OOFF + (lane & 7) * 16);
  usedN[lane] = 0; usedP[lane] = 0;
  if (lane < 8) { exN[lane] = ZOFF; exP[lane] = OOFF; spnN[lane] = 0; spnP[lane] = 0; }
  if (lane == 0) { exn = 0; exp_ = 0; }
  __syncthreads();

  unsigned fl = 0, ho = ZOFF;
  if (c < CONS) {
    int hp1 = (c >= 1) ? head_atom[c-1] : -1;
    int hp2 = (c >= 2) ? head_atom[c-2] : -1;
    bool fN1=false, fP1=false, fN2=false, fP2=false;
    const int res = lane & 7;                  // == atom & 7 for every k
    const unsigned long long clsmask = 0x0101010101010101ull << res;
    const unsigned long long lt = (1ull << lane) - 1ull;
    int cntN = 0, cntP = 0;
    for (int k = 0; k < NUM/64; ++k) {
      int a = k*64 + lane;
      bool ln = neg[(size_t)c*NUM + a] != 0.f;
      bool lp = pos[(size_t)c*NUM + a] != 0.f;
      bool i1 = (a == hp1);
      bool i2 = (a == hp2) && !i1;             // latest-update priority on dup heads
      fN1 |= __ballot(ln && i1) != 0ull; fP1 |= __ballot(lp && i1) != 0ull;
      fN2 |= __ballot(ln && i2) != 0ull; fP2 |= __ballot(lp && i2) != 0ull;
      bool kn = ln && !i1 && !i2;
      bool kp = lp && !i1 && !i2;
      unsigned long long mn = __ballot(kn) & clsmask;
      unsigned long long mp = __ballot(kp) & clsmask;
      if (kn) {                                // parallel residue-8 dealing
        int rr = cntN + (int)__popcll(mn & lt);
        if (rr < 8) { slotN[rr*8+res] = (unsigned short)(a*16); usedN[rr*8+res] = 1; }
        else if (rr < 20) spillN[res][rr-8] = (unsigned short)(a*16);
      }
      if (kp) {
        int rr = cntP + (int)__popcll(mp & lt);
        if (rr < 8) { slotP[rr*8+res] = (unsigned short)(a*16); usedP[rr*8+res] = 1; }
        else if (rr < 20) spillP[res][rr-8] = (unsigned short)(a*16);
      }
      cntN += (int)__popcll(mn); cntP += (int)__popcll(mp);
    }
    if (lane < 8) {                            // lane == residue here
      int sn = cntN - 8; if (sn < 0) sn = 0; if (sn > 12) sn = 12;
      int sp = cntP - 8; if (sp < 0) sp = 0; if (sp > 12) sp = 12;
      spnN[lane] = (unsigned char)sn; spnP[lane] = (unsigned char)sp;
    }
    __syncthreads();
    if (lane < 2) {                            // spill placement (serial, tiny)
      bool isP = lane == 1;
      unsigned short* slot = isP ? slotP : slotN;
      unsigned char*  used = isP ? usedP : usedN;
      unsigned char*  spn  = isP ? spnP  : spnN;
      unsigned short* exb  = isP ? exP   : exN;
      int e = 0, scan = 0;
      for (int r = 0; r < 8; ++r) {
        int ns = spn[r];
        for (int k = 0; k < ns; ++k) {
          unsigned short v = isP ? spillP[r][k] : spillN[r][k];
          while (scan < 64 && used[scan]) ++scan;
          if (scan < 64) { slot[scan] = v; used[scan] = 1; }
          else if (e < 8) exb[e++] = v;
        }
      }
      if (isP) exp_ = e; else exn = e;
    }
    __syncthreads();
    int hc = head_atom[c];
    fl = (head_sign[c] ? 1u : 0u)
       | (fN1?2u:0u) | (fP1?4u:0u) | (fN2?8u:0u) | (fP2?16u:0u);
    if (hc == hp1) fl |= 32u; else if (hc == hp2) fl |= 64u;
    fl |= ((unsigned)exn << 7) | ((unsigned)exp_ << 11);
    ho = (unsigned)hc * 16u;
  } else {
    fl = 0x8000u;                              // SKIP pad record
  }

  for (int t = lane; t < RSTR; t += 64) {
    unsigned v;
    if (t < 32) {
      int jp = t >> 4, gg = t & 15;
      v = (unsigned)slotN[32*jp + gg] | ((unsigned)slotN[32*jp + 16 + gg] << 16);
    } else if (t < 64) {
      int tp = t - 32, jp = tp >> 4, gg = tp & 15;
      v = (unsigned)slotP[32*jp + gg] | ((unsigned)slotP[32*jp + 16 + gg] << 16);
    } else if (t == 64) v = ho | (fl << 16);
    else if (t < 73) v = exN[t - 65];
    else if (t < 81) v = exP[t - 73];
    else v = 0;
    rec[t] = v;
  }
}

struct ENT { unsigned w0, w1, w2, w3, mh; };
struct RDv { h2 n0,n1,n2,n3,p0,p1,p2,p3,pv; unsigned mh, ho; };
struct ST  { h2 braw, prevraw; unsigned ho, flu; };

static __device__ __forceinline__ ENT ldent(const unsigned* ents, int c, int g) {
  const unsigned* rec = ents + (size_t)c * RSTR;
  ENT e;
  e.w0 = rec[g]; e.w1 = rec[16+g]; e.w2 = rec[32+g]; e.w3 = rec[48+g];
  e.mh = rec[64];
  return e;
}
// prp = pr4 | (pr4<<16): one add folds the row-pair offset into both packed
// addresses (carry-free: addr+12 < 65536). volatile reads pin 4-deep pipeline.
static __device__ __forceinline__ void issue_reads(const ENT& E, const char* Pb,
                                                   unsigned prp, RDv& R) {
  unsigned w0 = E.w0 + prp, w1 = E.w1 + prp;
  unsigned w2 = E.w2 + prp, w3 = E.w3 + prp;
  unsigned wm = E.mh + (prp & 0xFFFFu);        // ho+pr4 in low half, fl intact
  R.n0 = ldsv(Pb, w0 & 0xFFFFu);
  R.n1 = ldsv(Pb, w0 >> 16);
  R.n2 = ldsv(Pb, w1 & 0xFFFFu);
  R.n3 = ldsv(Pb, w1 >> 16);
  R.p0 = ldsv(Pb, w2 & 0xFFFFu);
  R.p1 = ldsv(Pb, w2 >> 16);
  R.p2 = ldsv(Pb, w3 & 0xFFFFu);
  R.p3 = ldsv(Pb, w3 >> 16);
  R.pv = ldsv(Pb, wm & 0xFFFFu);
  R.mh = E.mh; R.ho = wm & 0xFFFFu;
}
static __device__ __forceinline__ void combine(const RDv& R, const unsigned* ents,
                                               int c, const char* Pb, unsigned pr4, ST& S) {
  h2 aN = hmax2(hmax2(R.n0, R.n1), hmax2(R.n2, R.n3));
  h2 aP = hmin2(hmin2(R.p0, R.p1), hmin2(R.p2, R.p3));
  unsigned flu = ((unsigned)__builtin_amdgcn_readfirstlane((int)R.mh)) >> 16;
  if (flu & 0x7F80u) {                        // rare extras tail (uniform)
    const unsigned* rec = ents + (size_t)c * RSTR;
    unsigned xn = (flu >> 7) & 15u, xp = (flu >> 11) & 15u;
    for (unsigned j = 0; j < xn; ++j) aN = hmax2(aN, ldsv(Pb, rec[65+j] + pr4));
    for (unsigned j = 0; j < xp; ++j) aP = hmin2(aP, ldsv(Pb, rec[73+j] + pr4));
  }
  const h2 one2 = {(_Float16)1.f, (_Float16)1.f};
  h2 bp = hmax2(aN, one2 - aP);               // >= 0 by construction
  // reduce across the group's 16 slot-lanes: 8 within this half-wave
  // (lanes (l&~7)..(l|7), all same r2), then across halves via permlane32_swap.
  bp = dppmax<0xB1>(bp);                      // quad_perm xor1
  bp = dppmax<0x4E>(bp);                      // quad_perm xor2
  bp = dppmax<0x141>(bp);                     // row_half_mirror
  {
    auto sw = __builtin_amdgcn_permlane32_swap((int)h2u(bp), (int)h2u(bp), false, false);
    bp = hmax2(u2h((unsigned)sw[0]), u2h((unsigned)sw[1]));   // orientation-insensitive
  }
  S.braw = bp; S.prevraw = R.pv; S.ho = R.ho; S.flu = flu;
}
static __device__ __forceinline__ h2 finalize(const ST& S, h2 up1, h2 up2,
                                              char* Pb, int lane) {
  const h2 one2 = {(_Float16)1.f, (_Float16)1.f};
  unsigned fl = S.flu;
  h2 b = S.braw;
  if (fl & 0x1Eu) {                           // uniform: dependency within distance 2
    unsigned mN1 = 0u-((fl>>1)&1u), mP1 = 0u-((fl>>2)&1u);
    unsigned mN2 = 0u-((fl>>3)&1u), mP2 = 0u-((fl>>4)&1u);
    b = hmax2(b, u2h(h2u(up1) & mN1));
    b = hmax2(b, u2h(h2u(one2 - up1) & mP1));
    b = hmax2(b, u2h(h2u(up2) & mN2));
    b = hmax2(b, u2h(h2u(one2 - up2) & mP2));
  }
  h2 prev = S.prevraw;
  if (fl & 0x60u) {                           // uniform: head == recent head (rare)
    unsigned mR1 = 0u-((fl>>5)&1u), mR2 = 0u-((fl>>6)&1u), mRn = ~(mR1|mR2);
    prev = u2h((h2u(up1)&mR1) | (h2u(up2)&mR2) | (h2u(S.prevraw)&mRn));
  }
  unsigned ms = 0u-(fl&1u);
  unsigned hi = h2u(hmax2(prev, one2 - b));
  unsigned lo = h2u(hmin2(prev, b));
  h2 upd = u2h((hi&ms) | (lo&~ms));
  if ((lane & 39) == 0 && !(fl & 0x8000u))    // lanes 0,8,16,24: one per row-pair
    *(h2*)(Pb + S.ho) = upd;                  // S.ho already includes pr4
  return upd;
}

__global__ __launch_bounds__(64) void solve_kernel(
    const float* __restrict__ preds,
    const unsigned* __restrict__ ents,
    float* __restrict__ out) {
  __shared__ char Pb[LDSB];
  const int lane = threadIdx.x;
  // main-loop mapping: row-pair r2 = (lane>>3)&3, slot-lane g = (lane&7)|8*(lane>>5).
  // a slot group's 16 lanes split 8+8 across wave halves so each half-wave touches
  // 32 distinct banks (bank = 4*(atom&7) + r2) -> conflict-free slot reads.
  const unsigned pr4 = (unsigned)((lane >> 3) & 3) * 4u;
  const unsigned prp = pr4 | (pr4 << 16);
  const int g = (lane & 7) | ((lane >> 5) << 3);
  // staging mapping (independent of main loop)
  const int r2s = lane >> 4, cs = lane & 15;
  const size_t row0 = (size_t)blockIdx.x * ROWS;

  if (lane < 32) *(unsigned*)(Pb + ZOFF + lane*4) = 0u;                 // 8 zero atoms
  else           *(unsigned*)(Pb + OOFF + (lane-32)*4) = 0x3C003C00u;   // 8 one atoms

  // stage in: [atom][8 rows] fp16
  for (int i = 0; i < 16; ++i) {
    int a = i*32 + cs*2;
    float2 v0 = *(const float2*)(preds + (row0 + 2*r2s)     * NUM + a);
    float2 v1 = *(const float2*)(preds + (row0 + 2*r2s + 1) * NUM + a);
    h2 w0 = {(_Float16)v0.x, (_Float16)v1.x};
    h2 w1 = {(_Float16)v0.y, (_Float16)v1.y};
    *(h2*)(Pb + a*16 + r2s*4) = w0;
    *(h2*)(Pb + (a+1)*16 + r2s*4) = w1;
  }
  __syncthreads();

  // 4-deep pipeline (volatile-pinned): cons q->Ra, q+1->Rb, q+2->Rc, q+3->Rd.
  // reads(c) issued right after fin(c-3)  -> staleness window dist 1-2 (prep flags);
  // comb(c) consumes reads issued ~2 cons earlier (LDS latency hidden);
  // ldent(c) loaded 4 cons before use (L2/L3 latency hidden).
  ENT Ea = ldent(ents, 3, g), Eb = ldent(ents, 4, g);
  ENT Ec = ldent(ents, 5, g), Ed = ldent(ents, 6, g);
  RDv Ra, Rb, Rc, Rd; ST S;
  {
    ENT t0 = ldent(ents, 0, g), t1 = ldent(ents, 1, g), t2 = ldent(ents, 2, g);
    issue_reads(t0, Pb, prp, Ra);
    issue_reads(t1, Pb, prp, Rb);
    issue_reads(t2, Pb, prp, Rc);
  }
  h2 up1 = (h2)0.0f, up2 = (h2)0.0f;

  #pragma unroll 1
  for (int q = 0; q < CONS; q += 4) {
    combine(Ra, ents, q, Pb, pr4, S);
    { h2 u = finalize(S, up1, up2, Pb, lane); up2 = up1; up1 = u; }        // c=q
    issue_reads(Ea, Pb, prp, Rd);                                          // reads q+3
    Ea = ldent(ents, q+7, g);

    combine(Rb, ents, q+1, Pb, pr4, S);
    { h2 u = finalize(S, up1, up2, Pb, lane); up2 = up1; up1 = u; }        // c=q+1
    issue_reads(Eb, Pb, prp, Ra);                                          // reads q+4
    Eb = ldent(ents, q+8, g);

    combine(Rc, ents, q+2, Pb, pr4, S);
    { h2 u = finalize(S, up1, up2, Pb, lane); up2 = up1; up1 = u; }        // c=q+2
    issue_reads(Ec, Pb, prp, Rb);                                          // reads q+5
    Ec = ldent(ents, q+9, g);

    combine(Rd, ents, q+3, Pb, pr4, S);
    { h2 u = finalize(S, up1, up2, Pb, lane); up2 = up1; up1 = u; }        // c=q+3
    issue_reads(Ed, Pb, prp, Rc);                                          // reads q+6
    Ed = ldent(ents, q+10, g);
  }

  __syncthreads();
  for (int i = 0; i < 16; ++i) {
    int a = i*32 + cs*2;
    h2 w0 = *(const h2*)(Pb + a*16 + r2s*4);
    h2 w1 = *(const h2*)(Pb + (a+1)*16 + r2s*4);
    float2 v0 = {(float)w0.x, (float)w1.x};
    float2 v1 = {(float)w0.y, (float)w1.y};
    *(float2*)(out + (row0 + 2*r2s)     * NUM + a) = v0;
    *(float2*)(out + (row0 + 2*r2s + 1) * NUM + a) = v1;
  }
}

extern "C" void kernel_launch(void* const* d_in, const int* in_sizes, int n_in,
                              void* d_out, int out_size, void* d_ws, size_t ws_size,
                              hipStream_t stream) {
  (void)in_sizes; (void)n_in; (void)out_size; (void)ws_size;
  const float* preds     = (const float*)d_in[0];
  const float* pos       = (const float*)d_in[1];
  const float* neg       = (const float*)d_in[2];
  const int*   head_atom = (const int*)d_in[3];
  const int*   head_sign = (const int*)d_in[4];

  unsigned* ents = (unsigned*)d_ws;      // NPAD * RSTR * 4 ≈ 175 KB

  prep_kernel<<<NPAD, 64, 0, stream>>>(pos, neg, head_atom, head_sign, ents);
  solve_kernel<<<BATCH / ROWS, 64, 0, stream>>>(preds, ents, (float*)d_out);
}

// Round 16
// 296.471 us; speedup vs baseline: 1.2527x; 1.2527x over previous
//
#include <hip/hip_runtime.h>

#define BATCH 16384
#define NUM   512
#define CONS  512
#define ROWS  8                     // rows per wave/block
#define ZOFF  (NUM*16)              // 8192: 8 zero dummy atoms x 16B
#define OOFF  (NUM*16 + 128)        // 8320: 8 one dummy atoms x 16B
#define LDSB  (NUM*16 + 256)        // 8448 B
#define NPAD  520                   // 512 real + 8 pad records
#define RSTR  84                    // record words per constraint

typedef _Float16 h2 __attribute__((ext_vector_type(2)));
static __device__ __forceinline__ h2 u2h(unsigned u){ return __builtin_bit_cast(h2,u); }
static __device__ __forceinline__ unsigned h2u(h2 h){ return __builtin_bit_cast(unsigned,h); }
static __device__ __forceinline__ h2 hmax2(h2 a,h2 b){ return __builtin_elementwise_max(a,b); }
static __device__ __forceinline__ h2 hmin2(h2 a,h2 b){ return __builtin_elementwise_min(a,b); }
template<int C>
static __device__ __forceinline__ h2 dppmax(h2 x) {
  unsigned v = (unsigned)__builtin_amdgcn_mov_dpp((int)h2u(x), C, 0xF, 0xF, true);
  return hmax2(x, u2h(v));
}

// record (RSTR words per c):
// [0..15]=N steps(0,1) packed u16 pairs by g; [16..31]=N steps(2,3);
// [32..47]=P steps(0,1); [48..63]=P steps(2,3); [64]= ho | fl<<16;
// [65..72]=N extras; [73..80]=P extras; [81..83]=pad.
// fl: 0 sign |1 N1 |2 P1 |3 N2 |4 P2 |5 PR1 |6 PR2 |7-9 exN |10-12 exP
//     |13 skipN3 (slots 48-63 of N all dummy) |14 skipP3 |15 SKIP
__global__ __launch_bounds__(64) void prep_kernel(
    const float* __restrict__ pos, const float* __restrict__ neg,
    const int* __restrict__ head_atom, const int* __restrict__ head_sign,
    unsigned* __restrict__ ents) {
  int c = blockIdx.x, lane = threadIdx.x;
  unsigned* rec = ents + (size_t)c * RSTR;
  __shared__ unsigned short slotN[64], slotP[64];
  __shared__ unsigned char  usedN[64], usedP[64];
  __shared__ unsigned short spillN[8][12], spillP[8][12];
  __shared__ unsigned char  spnN[8], spnP[8];
  __shared__ unsigned short exN[8], exP[8];
  __shared__ int exn, exp_;
  slotN[lane] = (unsigned short)(ZOFF + (lane & 7) * 16);   // residue-matched dummies
  slotP[lane] = (unsigned short)(OOFF + (lane & 7) * 16);
  usedN[lane] = 0; usedP[lane] = 0;
  if (lane < 8) { exN[lane] = ZOFF; exP[lane] = OOFF; spnN[lane] = 0; spnP[lane] = 0; }
  if (lane == 0) { exn = 0; exp_ = 0; }
  __syncthreads();

  unsigned fl = 0, ho = ZOFF;
  if (c < CONS) {
    int hp1 = (c >= 1) ? head_atom[c-1] : -1;
    int hp2 = (c >= 2) ? head_atom[c-2] : -1;
    bool fN1=false, fP1=false, fN2=false, fP2=false;
    const int res = lane & 7;                  // == atom & 7 for every k
    const unsigned long long clsmask = 0x0101010101010101ull << res;
    const unsigned long long lt = (1ull << lane) - 1ull;
    int cntN = 0, cntP = 0;
    for (int k = 0; k < NUM/64; ++k) {
      int a = k*64 + lane;
      bool ln = neg[(size_t)c*NUM + a] != 0.f;
      bool lp = pos[(size_t)c*NUM + a] != 0.f;
      bool i1 = (a == hp1);
      bool i2 = (a == hp2) && !i1;             // latest-update priority on dup heads
      fN1 |= __ballot(ln && i1) != 0ull; fP1 |= __ballot(lp && i1) != 0ull;
      fN2 |= __ballot(ln && i2) != 0ull; fP2 |= __ballot(lp && i2) != 0ull;
      bool kn = ln && !i1 && !i2;
      bool kp = lp && !i1 && !i2;
      unsigned long long mn = __ballot(kn) & clsmask;
      unsigned long long mp = __ballot(kp) & clsmask;
      if (kn) {                                // parallel residue-8 dealing
        int rr = cntN + (int)__popcll(mn & lt);
        if (rr < 8) { slotN[rr*8+res] = (unsigned short)(a*16); usedN[rr*8+res] = 1; }
        else if (rr < 20) spillN[res][rr-8] = (unsigned short)(a*16);
      }
      if (kp) {
        int rr = cntP + (int)__popcll(mp & lt);
        if (rr < 8) { slotP[rr*8+res] = (unsigned short)(a*16); usedP[rr*8+res] = 1; }
        else if (rr < 20) spillP[res][rr-8] = (unsigned short)(a*16);
      }
      cntN += (int)__popcll(mn); cntP += (int)__popcll(mp);
    }
    if (lane < 8) {                            // lane == residue here
      int sn = cntN - 8; if (sn < 0) sn = 0; if (sn > 12) sn = 12;
      int sp = cntP - 8; if (sp < 0) sp = 0; if (sp > 12) sp = 12;
      spnN[lane] = (unsigned char)sn; spnP[lane] = (unsigned char)sp;
    }
    __syncthreads();
    if (lane < 2) {                            // spill placement (serial, tiny)
      bool isP = lane == 1;
      unsigned short* slot = isP ? slotP : slotN;
      unsigned char*  used = isP ? usedP : usedN;
      unsigned char*  spn  = isP ? spnP  : spnN;
      unsigned short* exb  = isP ? exP   : exN;
      int e = 0, scan = 0;
      for (int r = 0; r < 8; ++r) {
        int ns = spn[r];
        for (int k = 0; k < ns; ++k) {
          unsigned short v = isP ? spillP[r][k] : spillN[r][k];
          while (scan < 64 && used[scan]) ++scan;
          if (scan < 64) { slot[scan] = v; used[scan] = 1; }
          else if (e < 7) exb[e++] = v;        // cap 7 (3-bit count field)
        }
      }
      if (isP) exp_ = e; else exn = e;
    }
    __syncthreads();
    int hc = head_atom[c];
    fl = (head_sign[c] ? 1u : 0u)
       | (fN1?2u:0u) | (fP1?4u:0u) | (fN2?8u:0u) | (fP2?16u:0u);
    if (hc == hp1) fl |= 32u; else if (hc == hp2) fl |= 64u;
    fl |= ((unsigned)exn << 7) | ((unsigned)exp_ << 10);
    // exact emptiness of slot-levels 6-7 (post-spill) -> reader skips n3/p3
    bool u = false;
    if (lane < 16)      u = usedN[48 + lane] != 0;
    else if (lane < 32) u = usedP[48 + (lane - 16)] != 0;
    unsigned long long bb = __ballot(u);
    if (!(bb & 0x000000000000FFFFull)) fl |= 0x2000u;
    if (!(bb & 0x00000000FFFF0000ull)) fl |= 0x4000u;
    ho = (unsigned)hc * 16u;
  } else {
    fl = 0x8000u | 0x6000u;                    // SKIP pad record, skip n3/p3 too
  }

  for (int t = lane; t < RSTR; t += 64) {
    unsigned v;
    if (t < 32) {
      int jp = t >> 4, gg = t & 15;
      v = (unsigned)slotN[32*jp + gg] | ((unsigned)slotN[32*jp + 16 + gg] << 16);
    } else if (t < 64) {
      int tp = t - 32, jp = tp >> 4, gg = tp & 15;
      v = (unsigned)slotP[32*jp + gg] | ((unsigned)slotP[32*jp + 16 + gg] << 16);
    } else if (t == 64) v = ho | (fl << 16);
    else if (t < 73) v = exN[t - 65];
    else if (t < 81) v = exP[t - 73];
    else v = 0;
    rec[t] = v;
  }
}

struct ENT { unsigned w0, w1, w2, w3, mh; };
struct RDv { h2 n0,n1,n2,n3,p0,p1,p2,p3,pv; unsigned flu, ho; };
struct ST  { h2 braw, prevraw; unsigned ho, flu; };

static __device__ __forceinline__ ENT ldent(const unsigned* ents, int c, int g) {
  const unsigned* rec = ents + (size_t)c * RSTR;
  ENT e;
  e.w0 = rec[g]; e.w1 = rec[16+g]; e.w2 = rec[32+g]; e.w3 = rec[48+g];
  e.mh = rec[64];
  return e;
}
// prp = pr4 | (pr4<<16): one add folds the row-pair offset into both packed
// addresses (carry-free: addr+12 < 65536). sflu scalar-branches skip n3/p3.
static __device__ __forceinline__ void issue_reads(const ENT& E, const char* Pb,
                                                   unsigned prp, RDv& R) {
  unsigned sflu = ((unsigned)__builtin_amdgcn_readfirstlane((int)E.mh)) >> 16;
  unsigned w0 = E.w0 + prp, w1 = E.w1 + prp;
  unsigned w2 = E.w2 + prp, w3 = E.w3 + prp;
  unsigned wm = E.mh + (prp & 0xFFFFu);        // ho+pr4 in low half
  R.n0 = *(const h2*)(Pb + (w0 & 0xFFFFu));
  R.n1 = *(const h2*)(Pb + (w0 >> 16));
  R.n2 = *(const h2*)(Pb + (w1 & 0xFFFFu));
  if (!(sflu & 0x2000u)) R.n3 = *(const h2*)(Pb + (w1 >> 16));
  R.p0 = *(const h2*)(Pb + (w2 & 0xFFFFu));
  R.p1 = *(const h2*)(Pb + (w2 >> 16));
  R.p2 = *(const h2*)(Pb + (w3 & 0xFFFFu));
  if (!(sflu & 0x4000u)) R.p3 = *(const h2*)(Pb + (w3 >> 16));
  R.pv = *(const h2*)(Pb + (wm & 0xFFFFu));
  R.flu = sflu; R.ho = wm & 0xFFFFu;
}
static __device__ __forceinline__ void combine(const RDv& R, const unsigned* ents,
                                               int c, const char* Pb, unsigned pr4, ST& S) {
  unsigned flu = R.flu;
  h2 aN = hmax2(hmax2(R.n0, R.n1), R.n2);
  if (!(flu & 0x2000u)) aN = hmax2(aN, R.n3);
  h2 aP = hmin2(hmin2(R.p0, R.p1), R.p2);
  if (!(flu & 0x4000u)) aP = hmin2(aP, R.p3);
  if (flu & 0x1F80u) {                        // rare extras tail (uniform, bits 7-12)
    const unsigned* rec = ents + (size_t)c * RSTR;
    unsigned xn = (flu >> 7) & 7u, xp = (flu >> 10) & 7u;
    for (unsigned j = 0; j < xn; ++j) aN = hmax2(aN, *(const h2*)(Pb + (rec[65+j] + pr4)));
    for (unsigned j = 0; j < xp; ++j) aP = hmin2(aP, *(const h2*)(Pb + (rec[73+j] + pr4)));
  }
  const h2 one2 = {(_Float16)1.f, (_Float16)1.f};
  h2 bp = hmax2(aN, one2 - aP);               // >= 0 by construction
  // reduce across the group's 16 slot-lanes: 8 within this half-wave
  // (lanes (l&~7)..(l|7), all same r2), then across halves via permlane32_swap.
  bp = dppmax<0xB1>(bp);                      // quad_perm xor1
  bp = dppmax<0x4E>(bp);                      // quad_perm xor2
  bp = dppmax<0x141>(bp);                     // row_half_mirror
  {
    auto sw = __builtin_amdgcn_permlane32_swap((int)h2u(bp), (int)h2u(bp), false, false);
    bp = hmax2(u2h((unsigned)sw[0]), u2h((unsigned)sw[1]));   // orientation-insensitive
  }
  S.braw = bp; S.prevraw = R.pv; S.ho = R.ho; S.flu = flu;
}
static __device__ __forceinline__ h2 finalize(const ST& S, h2 up1, h2 up2,
                                              char* Pb, bool wl) {
  const h2 one2 = {(_Float16)1.f, (_Float16)1.f};
  unsigned fl = S.flu;
  h2 b = S.braw;
  if (fl & 0x1Eu) {                           // uniform: dependency within distance 2
    unsigned mN1 = 0u-((fl>>1)&1u), mP1 = 0u-((fl>>2)&1u);
    unsigned mN2 = 0u-((fl>>3)&1u), mP2 = 0u-((fl>>4)&1u);
    b = hmax2(b, u2h(h2u(up1) & mN1));
    b = hmax2(b, u2h(h2u(one2 - up1) & mP1));
    b = hmax2(b, u2h(h2u(up2) & mN2));
    b = hmax2(b, u2h(h2u(one2 - up2) & mP2));
  }
  h2 prev = S.prevraw;
  if (fl & 0x60u) {                           // uniform: head == recent head (rare)
    unsigned mR1 = 0u-((fl>>5)&1u), mR2 = 0u-((fl>>6)&1u), mRn = ~(mR1|mR2);
    prev = u2h((h2u(up1)&mR1) | (h2u(up2)&mR2) | (h2u(S.prevraw)&mRn));
  }
  unsigned ms = 0u-(fl&1u);
  unsigned hi = h2u(hmax2(prev, one2 - b));
  unsigned lo = h2u(hmin2(prev, b));
  h2 upd = u2h((hi&ms) | (lo&~ms));
  if (wl && !(fl & 0x8000u))                  // lanes 0,8,16,24: one per row-pair
    *(h2*)(Pb + S.ho) = upd;                  // S.ho already includes pr4
  return upd;
}

__global__ __launch_bounds__(64, 2) void solve_kernel(
    const float* __restrict__ preds,
    const unsigned* __restrict__ ents,
    float* __restrict__ out) {
  __shared__ char Pb[LDSB];
  const int lane = threadIdx.x;
  // main-loop mapping: row-pair r2 = (lane>>3)&3, slot-lane g = (lane&7)|8*(lane>>5).
  // a slot group's 16 lanes split 8+8 across wave halves so each half-wave touches
  // 32 distinct banks (bank = 4*(atom&7) + r2) -> conflict-free slot reads.
  const unsigned pr4 = (unsigned)((lane >> 3) & 3) * 4u;
  const unsigned prp = pr4 | (pr4 << 16);
  const int g = (lane & 7) | ((lane >> 5) << 3);
  const bool wl = (lane & 39) == 0;
  // staging mapping (independent of main loop)
  const int r2s = lane >> 4, cs = lane & 15;
  const size_t row0 = (size_t)blockIdx.x * ROWS;

  if (lane < 32) *(unsigned*)(Pb + ZOFF + lane*4) = 0u;                 // 8 zero atoms
  else           *(unsigned*)(Pb + OOFF + (lane-32)*4) = 0x3C003C00u;   // 8 one atoms

  // stage in: [atom][8 rows] fp16
  for (int i = 0; i < 16; ++i) {
    int a = i*32 + cs*2;
    float2 v0 = *(const float2*)(preds + (row0 + 2*r2s)     * NUM + a);
    float2 v1 = *(const float2*)(preds + (row0 + 2*r2s + 1) * NUM + a);
    h2 w0 = {(_Float16)v0.x, (_Float16)v1.x};
    h2 w1 = {(_Float16)v0.y, (_Float16)v1.y};
    *(h2*)(Pb + a*16 + r2s*4) = w0;
    *(h2*)(Pb + (a+1)*16 + r2s*4) = w1;
  }
  __syncthreads();

  // round-1 verified 2-deep rotation: reads(c) issued after fin(c-2),
  // staleness window dist 1-2 (prep flags); ldent 4-5 cons ahead.
  ENT E0 = ldent(ents, 0, g), E1 = ldent(ents, 1, g);
  ENT E2 = ldent(ents, 2, g), E3 = ldent(ents, 3, g);
  RDv RA, RB; ST S0, S1;
  issue_reads(E0, Pb, prp, RA);
  issue_reads(E1, Pb, prp, RB);
  combine(RA, ents, 0, Pb, pr4, S0);
  h2 up1 = (h2)0.0f, up2 = (h2)0.0f;

  #pragma unroll 1
  for (int i = 0; i < CONS; i += 2) {
    issue_reads(E2, Pb, prp, RA);                                      // reads(i+2)
    { h2 u = finalize(S0, up1, up2, Pb, wl); up2 = up1; up1 = u; }     // c=i
    combine(RB, ents, i+1, Pb, pr4, S1);
    E2 = ldent(ents, i+4, g);
    issue_reads(E3, Pb, prp, RB);                                      // reads(i+3)
    { h2 u = finalize(S1, up1, up2, Pb, wl); up2 = up1; up1 = u; }     // c=i+1
    combine(RA, ents, i+2, Pb, pr4, S0);
    E3 = ldent(ents, i+5, g);
  }

  __syncthreads();
  for (int i = 0; i < 16; ++i) {
    int a = i*32 + cs*2;
    h2 w0 = *(const h2*)(Pb + a*16 + r2s*4);
    h2 w1 = *(const h2*)(Pb + (a+1)*16 + r2s*4);
    float2 v0 = {(float)w0.x, (float)w1.x};
    float2 v1 = {(float)w0.y, (float)w1.y};
    *(float2*)(out + (row0 + 2*r2s)     * NUM + a) = v0;
    *(float2*)(out + (row0 + 2*r2s + 1) * NUM + a) = v1;
  }
}

extern "C" void kernel_launch(void* const* d_in, const int* in_sizes, int n_in,
                              void* d_out, int out_size, void* d_ws, size_t ws_size,
                              hipStream_t stream) {
  (void)in_sizes; (void)n_in; (void)out_size; (void)ws_size;
  const float* preds     = (const float*)d_in[0];
  const float* pos       = (const float*)d_in[1];
  const float* neg       = (const float*)d_in[2];
  const int*   head_atom = (const int*)d_in[3];
  const int*   head_sign = (const int*)d_in[4];

  unsigned* ents = (unsigned*)d_ws;      // NPAD * RSTR * 4 ≈ 175 KB

  prep_kernel<<<NPAD, 64, 0, stream>>>(pos, neg, head_atom, head_sign, ents);
  solve_kernel<<<BATCH / ROWS, 64, 0, stream>>>(preds, ents, (float*)d_out);
}

// Round 18
// 263.427 us; speedup vs baseline: 1.4099x; 1.1254x over previous
//
#include <hip/hip_runtime.h>

#define BATCH 16384
#define NUM   512
#define CONS  512
#define ROWS  8                     // rows per wave/block
#define ZOFF  (NUM*16)              // 8192: 8 zero dummy atoms x 16B
#define OOFF  (NUM*16 + 128)        // 8320: 8 one dummy atoms x 16B
#define LDSB  (NUM*16 + 256)        // 8448 B
#define NPAD  520                   // 512 real + 8 pad records
#define RSTR  84                    // record words per constraint

typedef _Float16 h2 __attribute__((ext_vector_type(2)));
static __device__ __forceinline__ h2 u2h(unsigned u){ return __builtin_bit_cast(h2,u); }
static __device__ __forceinline__ unsigned h2u(h2 h){ return __builtin_bit_cast(unsigned,h); }
static __device__ __forceinline__ h2 hmax2(h2 a,h2 b){ return __builtin_elementwise_max(a,b); }
static __device__ __forceinline__ h2 hmin2(h2 a,h2 b){ return __builtin_elementwise_min(a,b); }
template<int C>
static __device__ __forceinline__ h2 dppmax(h2 x) {
  unsigned v = (unsigned)__builtin_amdgcn_mov_dpp((int)h2u(x), C, 0xF, 0xF, true);
  return hmax2(x, u2h(v));
}

// record (RSTR words per c):
// [0..15]=N steps(0,1) packed u16 pairs by g; [16..31]=N steps(2,3);
// [32..47]=P steps(0,1); [48..63]=P steps(2,3); [64]= ho | fl<<16;
// [65..72]=N extras; [73..80]=P extras; [81..83]=pad.
// fl: 0 sign |1 N1 |2 P1 |3 N2 |4 P2 |5 PR1 |6 PR2 |7-10 exN |11-14 exP |15 SKIP
__global__ __launch_bounds__(64) void prep_kernel(
    const float* __restrict__ pos, const float* __restrict__ neg,
    const int* __restrict__ head_atom, const int* __restrict__ head_sign,
    unsigned* __restrict__ ents) {
  int c = blockIdx.x, lane = threadIdx.x;
  unsigned* rec = ents + (size_t)c * RSTR;
  __shared__ unsigned short slotN[64], slotP[64];
  __shared__ unsigned char  usedN[64], usedP[64];
  __shared__ unsigned short spillN[8][12], spillP[8][12];
  __shared__ unsigned char  spnN[8], spnP[8];
  __shared__ unsigned short exN[8], exP[8];
  __shared__ int exn, exp_;
  slotN[lane] = (unsigned short)(ZOFF + (lane & 7) * 16);   // residue-matched dummies
  slotP[lane] = (unsigned short)(OOFF + (lane & 7) * 16);
  usedN[lane] = 0; usedP[lane] = 0;
  if (lane < 8) { exN[lane] = ZOFF; exP[lane] = OOFF; spnN[lane] = 0; spnP[lane] = 0; }
  if (lane == 0) { exn = 0; exp_ = 0; }
  __syncthreads();

  unsigned fl = 0, ho = ZOFF;
  if (c < CONS) {
    int hp1 = (c >= 1) ? head_atom[c-1] : -1;
    int hp2 = (c >= 2) ? head_atom[c-2] : -1;
    bool fN1=false, fP1=false, fN2=false, fP2=false;
    const int res = lane & 7;                  // == atom & 7 for every k
    const unsigned long long clsmask = 0x0101010101010101ull << res;
    const unsigned long long lt = (1ull << lane) - 1ull;
    int cntN = 0, cntP = 0;
    for (int k = 0; k < NUM/64; ++k) {
      int a = k*64 + lane;
      bool ln = neg[(size_t)c*NUM + a] != 0.f;
      bool lp = pos[(size_t)c*NUM + a] != 0.f;
      bool i1 = (a == hp1);
      bool i2 = (a == hp2) && !i1;             // latest-update priority on dup heads
      fN1 |= __ballot(ln && i1) != 0ull; fP1 |= __ballot(lp && i1) != 0ull;
      fN2 |= __ballot(ln && i2) != 0ull; fP2 |= __ballot(lp && i2) != 0ull;
      bool kn = ln && !i1 && !i2;
      bool kp = lp && !i1 && !i2;
      unsigned long long mn = __ballot(kn) & clsmask;
      unsigned long long mp = __ballot(kp) & clsmask;
      if (kn) {                                // parallel residue-8 dealing
        int rr = cntN + (int)__popcll(mn & lt);
        if (rr < 8) { slotN[rr*8+res] = (unsigned short)(a*16); usedN[rr*8+res] = 1; }
        else if (rr < 20) spillN[res][rr-8] = (unsigned short)(a*16);
      }
      if (kp) {
        int rr = cntP + (int)__popcll(mp & lt);
        if (rr < 8) { slotP[rr*8+res] = (unsigned short)(a*16); usedP[rr*8+res] = 1; }
        else if (rr < 20) spillP[res][rr-8] = (unsigned short)(a*16);
      }
      cntN += (int)__popcll(mn); cntP += (int)__popcll(mp);
    }
    if (lane < 8) {                            // lane == residue here
      int sn = cntN - 8; if (sn < 0) sn = 0; if (sn > 12) sn = 12;
      int sp = cntP - 8; if (sp < 0) sp = 0; if (sp > 12) sp = 12;
      spnN[lane] = (unsigned char)sn; spnP[lane] = (unsigned char)sp;
    }
    __syncthreads();
    if (lane < 2) {                            // spill placement (serial, tiny)
      bool isP = lane == 1;
      unsigned short* slot = isP ? slotP : slotN;
      unsigned char*  used = isP ? usedP : usedN;
      unsigned char*  spn  = isP ? spnP  : spnN;
      unsigned short* exb  = isP ? exP   : exN;
      int e = 0, scan = 0;
      for (int r = 0; r < 8; ++r) {
        int ns = spn[r];
        for (int k = 0; k < ns; ++k) {
          unsigned short v = isP ? spillP[r][k] : spillN[r][k];
          while (scan < 64 && used[scan]) ++scan;
          if (scan < 64) { slot[scan] = v; used[scan] = 1; }
          else if (e < 8) exb[e++] = v;
        }
      }
      if (isP) exp_ = e; else exn = e;
    }
    __syncthreads();
    int hc = head_atom[c];
    fl = (head_sign[c] ? 1u : 0u)
       | (fN1?2u:0u) | (fP1?4u:0u) | (fN2?8u:0u) | (fP2?16u:0u);
    if (hc == hp1) fl |= 32u; else if (hc == hp2) fl |= 64u;
    fl |= ((unsigned)exn << 7) | ((unsigned)exp_ << 11);
    ho = (unsigned)hc * 16u;
  } else {
    fl = 0x8000u;                              // SKIP pad record
  }

  for (int t = lane; t < RSTR; t += 64) {
    unsigned v;
    if (t < 32) {
      int jp = t >> 4, gg = t & 15;
      v = (unsigned)slotN[32*jp + gg] | ((unsigned)slotN[32*jp + 16 + gg] << 16);
    } else if (t < 64) {
      int tp = t - 32, jp = tp >> 4, gg = tp & 15;
      v = (unsigned)slotP[32*jp + gg] | ((unsigned)slotP[32*jp + 16 + gg] << 16);
    } else if (t == 64) v = ho | (fl << 16);
    else if (t < 73) v = exN[t - 65];
    else if (t < 81) v = exP[t - 73];
    else v = 0;
    rec[t] = v;
  }
}

struct ENT { unsigned w0, w1, w2, w3, mh; };
struct RDv { h2 n0,n1,n2,n3,p0,p1,p2,p3,pv; unsigned mh, ho; };
struct ST  { h2 braw, prevraw; unsigned ho, flu; };

static __device__ __forceinline__ ENT ldent(const unsigned* ents, int c, int g) {
  const unsigned* rec = ents + (size_t)c * RSTR;
  ENT e;
  e.w0 = rec[g]; e.w1 = rec[16+g]; e.w2 = rec[32+g]; e.w3 = rec[48+g];
  e.mh = rec[64];
  return e;
}
// prp = pr4 | (pr4<<16): one add folds the row-pair offset into both packed
// addresses (carry-free: addr+12 < 65536). Unconditional 9 reads (no branches
// in the cluster; flu is consumed only in combine, 2 slots later).
static __device__ __forceinline__ void issue_reads(const ENT& E, const char* Pb,
                                                   unsigned prp, RDv& R) {
  unsigned w0 = E.w0 + prp, w1 = E.w1 + prp;
  unsigned w2 = E.w2 + prp, w3 = E.w3 + prp;
  unsigned wm = E.mh + (prp & 0xFFFFu);        // ho+pr4 in low half, fl intact
  R.n0 = *(const h2*)(Pb + (w0 & 0xFFFFu));
  R.n1 = *(const h2*)(Pb + (w0 >> 16));
  R.n2 = *(const h2*)(Pb + (w1 & 0xFFFFu));
  R.n3 = *(const h2*)(Pb + (w1 >> 16));
  R.p0 = *(const h2*)(Pb + (w2 & 0xFFFFu));
  R.p1 = *(const h2*)(Pb + (w2 >> 16));
  R.p2 = *(const h2*)(Pb + (w3 & 0xFFFFu));
  R.p3 = *(const h2*)(Pb + (w3 >> 16));
  R.pv = *(const h2*)(Pb + (wm & 0xFFFFu));
  R.mh = E.mh; R.ho = wm & 0xFFFFu;
}
static __device__ __forceinline__ void combine(const RDv& R, const unsigned* ents,
                                               int c, const char* Pb, unsigned pr4, ST& S) {
  h2 aN = hmax2(hmax2(R.n0, R.n1), hmax2(R.n2, R.n3));
  h2 aP = hmin2(hmin2(R.p0, R.p1), hmin2(R.p2, R.p3));
  unsigned flu = ((unsigned)__builtin_amdgcn_readfirstlane((int)R.mh)) >> 16;
  if (flu & 0x7F80u) {                        // rare extras tail (uniform)
    const unsigned* rec = ents + (size_t)c * RSTR;
    unsigned xn = (flu >> 7) & 15u, xp = (flu >> 11) & 15u;
    for (unsigned j = 0; j < xn; ++j) aN = hmax2(aN, *(const h2*)(Pb + (rec[65+j] + pr4)));
    for (unsigned j = 0; j < xp; ++j) aP = hmin2(aP, *(const h2*)(Pb + (rec[73+j] + pr4)));
  }
  const h2 one2 = {(_Float16)1.f, (_Float16)1.f};
  h2 bp = hmax2(aN, one2 - aP);               // >= 0 by construction
  // reduce across the group's 16 slot-lanes: 8 within this half-wave
  // (lanes (l&~7)..(l|7), all same r2), then across halves via permlane32_swap.
  bp = dppmax<0xB1>(bp);                      // quad_perm xor1
  bp = dppmax<0x4E>(bp);                      // quad_perm xor2
  bp = dppmax<0x141>(bp);                     // row_half_mirror
  {
    auto sw = __builtin_amdgcn_permlane32_swap((int)h2u(bp), (int)h2u(bp), false, false);
    bp = hmax2(u2h((unsigned)sw[0]), u2h((unsigned)sw[1]));   // orientation-insensitive
  }
  S.braw = bp; S.prevraw = R.pv; S.ho = R.ho; S.flu = flu;
}
static __device__ __forceinline__ h2 finalize(const ST& S, h2 up1, h2 up2,
                                              char* Pb, bool wl) {
  const h2 one2 = {(_Float16)1.f, (_Float16)1.f};
  unsigned fl = S.flu;
  h2 b = S.braw;
  if (fl & 0x1Eu) {                           // uniform: dependency within distance 2
    unsigned mN1 = 0u-((fl>>1)&1u), mP1 = 0u-((fl>>2)&1u);
    unsigned mN2 = 0u-((fl>>3)&1u), mP2 = 0u-((fl>>4)&1u);
    b = hmax2(b, u2h(h2u(up1) & mN1));
    b = hmax2(b, u2h(h2u(one2 - up1) & mP1));
    b = hmax2(b, u2h(h2u(up2) & mN2));
    b = hmax2(b, u2h(h2u(one2 - up2) & mP2));
  }
  h2 prev = S.prevraw;
  if (fl & 0x60u) {                           // uniform: head == recent head (rare)
    unsigned mR1 = 0u-((fl>>5)&1u), mR2 = 0u-((fl>>6)&1u), mRn = ~(mR1|mR2);
    prev = u2h((h2u(up1)&mR1) | (h2u(up2)&mR2) | (h2u(S.prevraw)&mRn));
  }
  unsigned ms = 0u-(fl&1u);
  unsigned hi = h2u(hmax2(prev, one2 - b));
  unsigned lo = h2u(hmin2(prev, b));
  h2 upd = u2h((hi&ms) | (lo&~ms));
  if (wl && !(fl & 0x8000u))                  // lanes 0,8,16,24: one per row-pair
    *(h2*)(Pb + S.ho) = upd;                  // S.ho already includes pr4
  return upd;
}

__global__ __launch_bounds__(64, 2) void solve_kernel(
    const float* __restrict__ preds,
    const unsigned* __restrict__ ents,
    float* __restrict__ out) {
  __shared__ char Pb[LDSB];
  const int lane = threadIdx.x;
  // main-loop mapping: row-pair r2 = (lane>>3)&3, slot-lane g = (lane&7)|8*(lane>>5).
  // a slot group's 16 lanes split 8+8 across wave halves so each half-wave touches
  // 32 distinct banks (bank = 4*(atom&7) + r2) -> conflict-free slot reads.
  const unsigned pr4 = (unsigned)((lane >> 3) & 3) * 4u;
  const unsigned prp = pr4 | (pr4 << 16);
  const int g = (lane & 7) | ((lane >> 5) << 3);
  const bool wl = (lane & 39) == 0;
  // staging mapping (independent of main loop)
  const int r2s = lane >> 4, cs = lane & 15;
  const size_t row0 = (size_t)blockIdx.x * ROWS;

  if (lane < 32) *(unsigned*)(Pb + ZOFF + lane*4) = 0u;                 // 8 zero atoms
  else           *(unsigned*)(Pb + OOFF + (lane-32)*4) = 0x3C003C00u;   // 8 one atoms

  // stage in: [atom][8 rows] fp16
  for (int i = 0; i < 16; ++i) {
    int a = i*32 + cs*2;
    float2 v0 = *(const float2*)(preds + (row0 + 2*r2s)     * NUM + a);
    float2 v1 = *(const float2*)(preds + (row0 + 2*r2s + 1) * NUM + a);
    h2 w0 = {(_Float16)v0.x, (_Float16)v1.x};
    h2 w1 = {(_Float16)v0.y, (_Float16)v1.y};
    *(h2*)(Pb + a*16 + r2s*4) = w0;
    *(h2*)(Pb + (a+1)*16 + r2s*4) = w1;
  }
  __syncthreads();

  // round-1 verified 2-deep rotation: reads(c) issued after fin(c-2),
  // staleness window dist 1-2 (prep flags); ldent 4-5 cons ahead.
  ENT E0 = ldent(ents, 0, g), E1 = ldent(ents, 1, g);
  ENT E2 = ldent(ents, 2, g), E3 = ldent(ents, 3, g);
  RDv RA, RB; ST S0, S1;
  issue_reads(E0, Pb, prp, RA);
  issue_reads(E1, Pb, prp, RB);
  combine(RA, ents, 0, Pb, pr4, S0);
  h2 up1 = (h2)0.0f, up2 = (h2)0.0f;

  #pragma unroll 1
  for (int i = 0; i < CONS; i += 2) {
    issue_reads(E2, Pb, prp, RA);                                      // reads(i+2)
    { h2 u = finalize(S0, up1, up2, Pb, wl); up2 = up1; up1 = u; }     // c=i
    combine(RB, ents, i+1, Pb, pr4, S1);
    E2 = ldent(ents, i+4, g);
    issue_reads(E3, Pb, prp, RB);                                      // reads(i+3)
    { h2 u = finalize(S1, up1, up2, Pb, wl); up2 = up1; up1 = u; }     // c=i+1
    combine(RA, ents, i+2, Pb, pr4, S0);
    E3 = ldent(ents, i+5, g);
  }

  __syncthreads();
  for (int i = 0; i < 16; ++i) {
    int a = i*32 + cs*2;
    h2 w0 = *(const h2*)(Pb + a*16 + r2s*4);
    h2 w1 = *(const h2*)(Pb + (a+1)*16 + r2s*4);
    float2 v0 = {(float)w0.x, (float)w1.x};
    float2 v1 = {(float)w0.y, (float)w1.y};
    *(float2*)(out + (row0 + 2*r2s)     * NUM + a) = v0;
    *(float2*)(out + (row0 + 2*r2s + 1) * NUM + a) = v1;
  }
}

extern "C" void kernel_launch(void* const* d_in, const int* in_sizes, int n_in,
                              void* d_out, int out_size, void* d_ws, size_t ws_size,
                              hipStream_t stream) {
  (void)in_sizes; (void)n_in; (void)out_size; (void)ws_size;
  const float* preds     = (const float*)d_in[0];
  const float* pos       = (const float*)d_in[1];
  const float* neg       = (const float*)d_in[2];
  const int*   head_atom = (const int*)d_in[3];
  const int*   head_sign = (const int*)d_in[4];

  unsigned* ents = (unsigned*)d_ws;      // NPAD * RSTR * 4 ≈ 175 KB

  prep_kernel<<<NPAD, 64, 0, stream>>>(pos, neg, head_atom, head_sign, ents);
  solve_kernel<<<BATCH / ROWS, 64, 0, stream>>>(preds, ents, (float*)d_out);
}